// Round 1
// baseline (435.647 us; speedup 1.0000x reference)
//
#include <hip/hip_runtime.h>
#include <hip/hip_bf16.h>

// Problem dims (AttentionLayer): B=4, S=2048, D=1024, H=16, HD=64
#define BB 4
#define SS 2048
#define DD 1024
#define HH 16
#define HDD 64
#define MM (BB*SS)   // 8192 rows

typedef __attribute__((ext_vector_type(8))) short short8;
typedef __attribute__((ext_vector_type(4))) float f32x4;
typedef __attribute__((ext_vector_type(4))) int int4v;

__device__ __forceinline__ ushort f2bf(float f) {
  union { float f; uint u; } v; v.f = f;
  uint u = v.u;
  uint r = (u + 0x7FFFu + ((u >> 16) & 1u)) >> 16;  // RNE
  return (ushort)r;
}

// ---------------- prep: fp32 -> bf16 convert (states) ----------------
__global__ __launch_bounds__(256) void k_convert(const float* __restrict__ in,
                                                 ushort* __restrict__ out, int n4) {
  int i = blockIdx.x * 256 + threadIdx.x;
  if (i >= n4) return;
  float4 v = ((const float4*)in)[i];
  uint lo = (uint)f2bf(v.x) | ((uint)f2bf(v.y) << 16);
  uint hi = (uint)f2bf(v.z) | ((uint)f2bf(v.w) << 16);
  ((uint2*)out)[i] = make_uint2(lo, hi);
}

// ---------------- prep: transpose+convert weights W[K][N] -> Wt[N][K] bf16 ----------------
__global__ __launch_bounds__(256) void k_transpose(const float* __restrict__ W0, const float* __restrict__ W1,
                                                   const float* __restrict__ W2, const float* __restrict__ W3,
                                                   ushort* __restrict__ T0, ushort* __restrict__ T1,
                                                   ushort* __restrict__ T2, ushort* __restrict__ T3) {
  __shared__ float t[32][33];
  const float* W; ushort* T;
  switch (blockIdx.z) {
    case 0: W = W0; T = T0; break;
    case 1: W = W1; T = T1; break;
    case 2: W = W2; T = T2; break;
    default: W = W3; T = T3; break;
  }
  int tx = threadIdx.x, ty = threadIdx.y;   // 32 x 8
  int x = blockIdx.x * 32 + tx;
  int y0 = blockIdx.y * 32;
#pragma unroll
  for (int j = 0; j < 32; j += 8) t[ty + j][tx] = W[(y0 + ty + j) * DD + x];
  __syncthreads();
#pragma unroll
  for (int j = 0; j < 32; j += 8)
    T[(blockIdx.x * 32 + ty + j) * DD + y0 + tx] = f2bf(t[tx][ty + j]);
}

// ---------------- shared GEMM mainloop: C[128,128] = A[128,K] * Bt[128,K]^T ----------------
// A, Bt row-major bf16 with leading dim DD=1024. acc[i][j] covers 16x16 tile (i=m, j=n).
__device__ __forceinline__ void gemm_tile(const ushort* __restrict__ Arow,
                                          const ushort* __restrict__ Brow,
                                          ushort (*Al)[40], ushort (*Bl)[40],
                                          f32x4 acc[4][4]) {
  int tid = threadIdx.x;
  int lane = tid & 63, w = tid >> 6;
  int wm = w >> 1, wn = w & 1;
  int lrow = lane & 15, lgrp = lane >> 4;
#pragma unroll
  for (int i = 0; i < 4; i++)
#pragma unroll
    for (int j = 0; j < 4; j++)
#pragma unroll
      for (int r = 0; r < 4; r++) acc[i][j][r] = 0.f;

  int srow = tid >> 2;          // 0..63
  int scol = (tid & 3) * 8;     // 0,8,16,24

  for (int kk = 0; kk < DD; kk += 32) {
#pragma unroll
    for (int p = 0; p < 2; p++) {
      int r = srow + p * 64;
      *(int4v*)&Al[r][scol] = *(const int4v*)(Arow + (size_t)r * DD + kk + scol);
      *(int4v*)&Bl[r][scol] = *(const int4v*)(Brow + (size_t)r * DD + kk + scol);
    }
    __syncthreads();
    short8 a[4], b[4];
#pragma unroll
    for (int i = 0; i < 4; i++) a[i] = *(const short8*)&Al[wm * 64 + i * 16 + lrow][lgrp * 8];
#pragma unroll
    for (int j = 0; j < 4; j++) b[j] = *(const short8*)&Bl[wn * 64 + j * 16 + lrow][lgrp * 8];
#pragma unroll
    for (int i = 0; i < 4; i++)
#pragma unroll
      for (int j = 0; j < 4; j++)
        acc[i][j] = __builtin_amdgcn_mfma_f32_16x16x32_bf16(a[i], b[j], acc[i][j], 0, 0, 0);
    __syncthreads();
  }
}

// ---------------- QKV projection: X @ {Wq,Wk,Wv} -> Q/K/V in [B,H,S,64] bf16 ----------------
__global__ __launch_bounds__(256) void k_qkv(const ushort* __restrict__ X,
                                             const ushort* __restrict__ Wqt,
                                             const ushort* __restrict__ Wkt,
                                             const ushort* __restrict__ Wvt,
                                             ushort* __restrict__ Q,
                                             ushort* __restrict__ K,
                                             ushort* __restrict__ V) {
  __shared__ ushort Al[128][40];
  __shared__ ushort Bl[128][40];
  const ushort* Wt; ushort* Out;
  switch (blockIdx.z) {
    case 0: Wt = Wqt; Out = Q; break;
    case 1: Wt = Wkt; Out = K; break;
    default: Wt = Wvt; Out = V; break;
  }
  f32x4 acc[4][4];
  gemm_tile(X + (size_t)blockIdx.x * 128 * DD, Wt + (size_t)blockIdx.y * 128 * DD, Al, Bl, acc);
  int lane = threadIdx.x & 63, w = threadIdx.x >> 6;
  int wm = w >> 1, wn = w & 1, lrow = lane & 15, lgrp = lane >> 4;
  int m0 = blockIdx.x * 128 + wm * 64, n0 = blockIdx.y * 128 + wn * 64;
#pragma unroll
  for (int i = 0; i < 4; i++)
#pragma unroll
    for (int j = 0; j < 4; j++)
#pragma unroll
      for (int r = 0; r < 4; r++) {
        int row = m0 + i * 16 + lgrp * 4 + r;   // global m (b*S+s)
        int col = n0 + j * 16 + lrow;            // global n (h*64+hd)
        int b = row >> 11, s = row & 2047, h = col >> 6, hd = col & 63;
        Out[(((size_t)(b * HH + h) * SS) + s) * HDD + hd] = f2bf(acc[i][j][r]);
      }
}

// ---------------- flash attention, causal, Q/K/V in [B,H,S,64] bf16 -> Ctx [B,S,D] bf16 ----------------
__global__ __launch_bounds__(256) void k_attn(const ushort* __restrict__ Q,
                                              const ushort* __restrict__ K,
                                              const ushort* __restrict__ V,
                                              ushort* __restrict__ Ctx) {
  __shared__ ushort Kl[64][72];
  __shared__ ushort Vt[64][72];   // Vt[hd][kv]
  __shared__ ushort Pl[4][16][72];
  int bh = blockIdx.y;
  int b = bh >> 4, h = bh & 15;
  int qbase = blockIdx.x * 64;
  int tid = threadIdx.x, lane = tid & 63, w = tid >> 6;
  int lrow = lane & 15, lgrp = lane >> 4;

  // Q fragments for this wave's 16 rows
  const ushort* qp = Q + ((size_t)bh * SS + qbase + w * 16 + lrow) * HDD + lgrp * 8;
  short8 qf[2];
  qf[0] = *(const short8*)qp;
  qf[1] = *(const short8*)(qp + 32);

  float m_run[4], l_run[4];
  f32x4 o[4];
#pragma unroll
  for (int r = 0; r < 4; r++) { m_run[r] = -1e30f; l_run[r] = 0.f; }
#pragma unroll
  for (int t = 0; t < 4; t++)
#pragma unroll
    for (int r = 0; r < 4; r++) o[t][r] = 0.f;

  int ntile = blockIdx.x + 1;
  const ushort* Kbase = K + (size_t)bh * SS * HDD;
  const ushort* Vbase = V + (size_t)bh * SS * HDD;

  for (int kt = 0; kt < ntile; kt++) {
    int kb = kt * 64;
    // stage K tile [64][64] and V^T tile
    {
      int rr = tid >> 3;            // 0..31
      int c8 = (tid & 7) * 8;       // 0..56
#pragma unroll
      for (int p = 0; p < 2; p++) {
        int r = rr + p * 32;
        *(int4v*)&Kl[r][c8] = *(const int4v*)(Kbase + (size_t)(kb + r) * HDD + c8);
        short8 vv = *(const short8*)(Vbase + (size_t)(kb + r) * HDD + c8);
#pragma unroll
        for (int j = 0; j < 8; j++) Vt[c8 + j][r] = (ushort)vv[j];
      }
    }
    __syncthreads();

    // scores: S[16q x 64kv] via mfma(Q, Kfrag)
    f32x4 sc[4];
#pragma unroll
    for (int t = 0; t < 4; t++) {
      f32x4 s4;
#pragma unroll
      for (int r = 0; r < 4; r++) s4[r] = 0.f;
#pragma unroll
      for (int c = 0; c < 2; c++) {
        short8 kfrag = *(const short8*)&Kl[lrow + 16 * t][lgrp * 8 + 32 * c];
        s4 = __builtin_amdgcn_mfma_f32_16x16x32_bf16(qf[c], kfrag, s4, 0, 0, 0);
      }
      sc[t] = s4;
    }

    // mask + scale + online softmax (rows = lgrp*4+r, cols = lrow+16t)
    int qrow0 = qbase + w * 16 + lgrp * 4;
    float rm[4];
#pragma unroll
    for (int r = 0; r < 4; r++) rm[r] = -1e30f;
    float p[4][4];
#pragma unroll
    for (int t = 0; t < 4; t++) {
      int kv = kb + lrow + 16 * t;
#pragma unroll
      for (int r = 0; r < 4; r++) {
        float v = sc[t][r] * 0.125f;
        if (kv > qrow0 + r) v = -1e30f;
        p[t][r] = v;
        rm[r] = fmaxf(rm[r], v);
      }
    }
#pragma unroll
    for (int d = 1; d < 16; d <<= 1)
#pragma unroll
      for (int r = 0; r < 4; r++) rm[r] = fmaxf(rm[r], __shfl_xor(rm[r], d, 64));
    float sca[4], rs[4];
#pragma unroll
    for (int r = 0; r < 4; r++) {
      float mn = fmaxf(m_run[r], rm[r]);
      sca[r] = __expf(m_run[r] - mn);
      m_run[r] = mn;
      rs[r] = 0.f;
    }
#pragma unroll
    for (int t = 0; t < 4; t++)
#pragma unroll
      for (int r = 0; r < 4; r++) {
        float e = __expf(p[t][r] - m_run[r]);
        p[t][r] = e;
        rs[r] += e;
      }
#pragma unroll
    for (int d = 1; d < 16; d <<= 1)
#pragma unroll
      for (int r = 0; r < 4; r++) rs[r] += __shfl_xor(rs[r], d, 64);
#pragma unroll
    for (int r = 0; r < 4; r++) l_run[r] = l_run[r] * sca[r] + rs[r];
#pragma unroll
    for (int t = 0; t < 4; t++)
#pragma unroll
      for (int r = 0; r < 4; r++) o[t][r] *= sca[r];

    // write P (bf16) to LDS in [q][kv] layout
#pragma unroll
    for (int t = 0; t < 4; t++)
#pragma unroll
      for (int r = 0; r < 4; r++)
        Pl[w][lgrp * 4 + r][lrow + 16 * t] = f2bf(p[t][r]);
    __syncthreads();

    // PV: O[16q x 64hd] += P[16q x 64kv] @ V[64kv x 64hd]
    short8 pa[2];
    pa[0] = *(const short8*)&Pl[w][lrow][lgrp * 8];
    pa[1] = *(const short8*)&Pl[w][lrow][lgrp * 8 + 32];
#pragma unroll
    for (int t = 0; t < 4; t++) {
#pragma unroll
      for (int c = 0; c < 2; c++) {
        short8 vfrag = *(const short8*)&Vt[lrow + 16 * t][lgrp * 8 + 32 * c];
        o[t] = __builtin_amdgcn_mfma_f32_16x16x32_bf16(pa[c], vfrag, o[t], 0, 0, 0);
      }
    }
    __syncthreads();
  }

  // epilogue: Ctx[b][s][h*64+hd]
  float inv[4];
#pragma unroll
  for (int r = 0; r < 4; r++) inv[r] = 1.f / l_run[r];
  ushort* cp = Ctx + ((size_t)b * SS + qbase + w * 16) * DD + h * HDD;
#pragma unroll
  for (int t = 0; t < 4; t++)
#pragma unroll
    for (int r = 0; r < 4; r++)
      cp[(size_t)(lgrp * 4 + r) * DD + lrow + 16 * t] = f2bf(o[t][r] * inv[r]);
}

// ---------------- output projection: Ctx @ Wo -> out fp32 [B,S,D] ----------------
__global__ __launch_bounds__(256) void k_oproj(const ushort* __restrict__ Ctx,
                                               const ushort* __restrict__ Wot,
                                               float* __restrict__ Outp) {
  __shared__ ushort Al[128][40];
  __shared__ ushort Bl[128][40];
  f32x4 acc[4][4];
  gemm_tile(Ctx + (size_t)blockIdx.x * 128 * DD, Wot + (size_t)blockIdx.y * 128 * DD, Al, Bl, acc);
  int lane = threadIdx.x & 63, w = threadIdx.x >> 6;
  int wm = w >> 1, wn = w & 1, lrow = lane & 15, lgrp = lane >> 4;
  int m0 = blockIdx.x * 128 + wm * 64, n0 = blockIdx.y * 128 + wn * 64;
#pragma unroll
  for (int i = 0; i < 4; i++)
#pragma unroll
    for (int j = 0; j < 4; j++)
#pragma unroll
      for (int r = 0; r < 4; r++) {
        int row = m0 + i * 16 + lgrp * 4 + r;
        int col = n0 + j * 16 + lrow;
        Outp[(size_t)row * DD + col] = acc[i][j][r];
      }
}

// ---------------- launch ----------------
extern "C" void kernel_launch(void* const* d_in, const int* in_sizes, int n_in,
                              void* d_out, int out_size, void* d_ws, size_t ws_size,
                              hipStream_t stream) {
  const float* states = (const float*)d_in[0];
  // d_in[1] = mask (causal tril) — hardcoded in kernel
  const float* Wq = (const float*)d_in[2];
  const float* Wk = (const float*)d_in[3];
  const float* Wv = (const float*)d_in[4];
  const float* Wo = (const float*)d_in[5];
  float* outp = (float*)d_out;

  char* ws = (char*)d_ws;
  const size_t XBF = 0;                 // 16 MB  (8192x1024 bf16)
  const size_t WQT = 16777216;          // 2 MB each
  const size_t WKT = WQT + 2097152;
  const size_t WVT = WKT + 2097152;
  const size_t WOT = WVT + 2097152;
  const size_t QO  = WOT + 2097152;     // 16 MB each, [B,H,S,64]
  const size_t KO  = QO + 16777216;
  const size_t VO  = KO + 16777216;
  const size_t CTX = VO + 16777216;     // 16 MB, [B,S,D]

  ushort* Xbf = (ushort*)(ws + XBF);
  ushort* Wqt = (ushort*)(ws + WQT);
  ushort* Wkt = (ushort*)(ws + WKT);
  ushort* Wvt = (ushort*)(ws + WVT);
  ushort* Wot = (ushort*)(ws + WOT);
  ushort* Qb  = (ushort*)(ws + QO);
  ushort* Kb  = (ushort*)(ws + KO);
  ushort* Vb  = (ushort*)(ws + VO);
  ushort* Ctb = (ushort*)(ws + CTX);

  k_convert<<<(MM * DD / 4 + 255) / 256, 256, 0, stream>>>(states, Xbf, MM * DD / 4);
  k_transpose<<<dim3(32, 32, 4), dim3(32, 8), 0, stream>>>(Wq, Wk, Wv, Wo, Wqt, Wkt, Wvt, Wot);
  k_qkv<<<dim3(MM / 128, DD / 128, 3), 256, 0, stream>>>(Xbf, Wqt, Wkt, Wvt, Qb, Kb, Vb);
  k_attn<<<dim3(SS / 64, BB * HH), 256, 0, stream>>>(Qb, Kb, Vb, Ctb);
  k_oproj<<<dim3(MM / 128, DD / 128), 256, 0, stream>>>(Ctb, Wot, outp);
}

// Round 2
// 283.198 us; speedup vs baseline: 1.5383x; 1.5383x over previous
//
#include <hip/hip_runtime.h>
#include <hip/hip_bf16.h>

// Problem dims (AttentionLayer): B=4, S=2048, D=1024, H=16, HD=64
#define BB 4
#define SS 2048
#define DD 1024
#define HH 16
#define HDD 64
#define MM (BB*SS)   // 8192 rows

typedef __attribute__((ext_vector_type(8))) short short8;
typedef __attribute__((ext_vector_type(4))) float f32x4;
typedef __attribute__((ext_vector_type(4))) int int4v;

__device__ __forceinline__ ushort f2bf(float f) {
  union { float f; uint u; } v; v.f = f;
  uint u = v.u;
  uint r = (u + 0x7FFFu + ((u >> 16) & 1u)) >> 16;  // RNE
  return (ushort)r;
}

__device__ __forceinline__ void gload16(void* lds, const void* g) {
  __builtin_amdgcn_global_load_lds((const __attribute__((address_space(1))) void*)g,
                                   (__attribute__((address_space(3))) void*)lds, 16, 0, 0);
}

// ---------------- prep: fp32 -> bf16 convert (states) ----------------
__global__ __launch_bounds__(256) void k_convert(const float* __restrict__ in,
                                                 ushort* __restrict__ out, int n4) {
  int i = blockIdx.x * 256 + threadIdx.x;
  if (i >= n4) return;
  float4 v = ((const float4*)in)[i];
  uint lo = (uint)f2bf(v.x) | ((uint)f2bf(v.y) << 16);
  uint hi = (uint)f2bf(v.z) | ((uint)f2bf(v.w) << 16);
  ((uint2*)out)[i] = make_uint2(lo, hi);
}

// ---------------- prep: transpose+convert weights W[K][N] -> Wt[N][K] bf16 ----------------
__global__ __launch_bounds__(256) void k_transpose(const float* __restrict__ W0, const float* __restrict__ W1,
                                                   const float* __restrict__ W2, const float* __restrict__ W3,
                                                   ushort* __restrict__ T0, ushort* __restrict__ T1,
                                                   ushort* __restrict__ T2, ushort* __restrict__ T3) {
  __shared__ float t[32][33];
  const float* W; ushort* T;
  switch (blockIdx.z) {
    case 0: W = W0; T = T0; break;
    case 1: W = W1; T = T1; break;
    case 2: W = W2; T = T2; break;
    default: W = W3; T = T3; break;
  }
  int tx = threadIdx.x, ty = threadIdx.y;   // 32 x 8
  int x = blockIdx.x * 32 + tx;
  int y0 = blockIdx.y * 32;
#pragma unroll
  for (int j = 0; j < 32; j += 8) t[ty + j][tx] = W[(y0 + ty + j) * DD + x];
  __syncthreads();
#pragma unroll
  for (int j = 0; j < 32; j += 8)
    T[(blockIdx.x * 32 + ty + j) * DD + y0 + tx] = f2bf(t[tx][ty + j]);
}

// ---------------- V transpose: V[bh][s][64] -> Vt[bh][64][S] (bf16) ----------------
__global__ __launch_bounds__(256) void k_vtrans(const ushort* __restrict__ V,
                                                ushort* __restrict__ Vt) {
  __shared__ ushort t[64][72];
  int bh = blockIdx.y;
  int s0 = blockIdx.x * 64;
  int tid = threadIdx.x;
  int r = tid >> 3, c8 = (tid & 7) * 8;
  const ushort* vp = V + (size_t)bh * SS * HDD;
#pragma unroll
  for (int p = 0; p < 2; p++) {
    int row = r + p * 32;
    *(int4v*)&t[row][c8] = *(const int4v*)(vp + (size_t)(s0 + row) * HDD + c8);
  }
  __syncthreads();
  int hd = tid >> 2, sc = (tid & 3) * 16;
  ushort tmp[16];
#pragma unroll
  for (int j = 0; j < 16; j++) tmp[j] = t[sc + j][hd];
  ushort* op = Vt + ((size_t)bh * HDD + hd) * SS + s0 + sc;
  *(int4v*)op = *(int4v*)tmp;
  *(int4v*)(op + 8) = *(int4v*)(tmp + 8);
}

// ---------------- shared GEMM mainloop (m97-style): C[128,128] = A[128,K] * Bt[128,K]^T ----------------
// global_load_lds staging, linear LDS [128][32] per buffer, 2-phase double buffer.
__device__ __forceinline__ void gemm_tile(const ushort* __restrict__ Arow,
                                          const ushort* __restrict__ Brow,
                                          ushort* Al, ushort* Bl,   // each [2][128*32]
                                          f32x4 acc[4][4]) {
  int tid = threadIdx.x;
  int lane = tid & 63, w = tid >> 6;
  int wm = w >> 1, wn = w & 1;
  int lrow = lane & 15, lgrp = lane >> 4;
#pragma unroll
  for (int i = 0; i < 4; i++)
#pragma unroll
    for (int j = 0; j < 4; j++)
#pragma unroll
      for (int r = 0; r < 4; r++) acc[i][j][r] = 0.f;

  int srow = lane >> 2;            // 0..15
  int scolb = (lane & 3) * 16;     // byte col within 64B row-chunk
  const char* A8 = (const char*)Arow;
  const char* B8 = (const char*)Brow;

  // prologue: stage kk=0 into buf 0 (wave w does insts w*2, w*2+1)
#pragma unroll
  for (int ii = 0; ii < 2; ii++) {
    int i = w * 2 + ii;
    gload16(Al + i * 512, A8 + (size_t)(i * 16 + srow) * (DD * 2) + scolb);
    gload16(Bl + i * 512, B8 + (size_t)(i * 16 + srow) * (DD * 2) + scolb);
  }
  __syncthreads();

  for (int kk = 0; kk < DD; kk += 32) {
    int cur = (kk >> 5) & 1;
    if (kk + 32 < DD) {
#pragma unroll
      for (int ii = 0; ii < 2; ii++) {
        int i = w * 2 + ii;
        gload16(Al + (cur ^ 1) * 4096 + i * 512,
                A8 + (size_t)(i * 16 + srow) * (DD * 2) + (kk + 32) * 2 + scolb);
        gload16(Bl + (cur ^ 1) * 4096 + i * 512,
                B8 + (size_t)(i * 16 + srow) * (DD * 2) + (kk + 32) * 2 + scolb);
      }
    }
    short8 a[4], b[4];
#pragma unroll
    for (int i = 0; i < 4; i++) a[i] = *(const short8*)&Al[cur * 4096 + (wm * 64 + i * 16 + lrow) * 32 + lgrp * 8];
#pragma unroll
    for (int j = 0; j < 4; j++) b[j] = *(const short8*)&Bl[cur * 4096 + (wn * 64 + j * 16 + lrow) * 32 + lgrp * 8];
#pragma unroll
    for (int i = 0; i < 4; i++)
#pragma unroll
      for (int j = 0; j < 4; j++)
        acc[i][j] = __builtin_amdgcn_mfma_f32_16x16x32_bf16(a[i], b[j], acc[i][j], 0, 0, 0);
    __syncthreads();
  }
}

// ---------------- QKV projection ----------------
__global__ __launch_bounds__(256) void k_qkv(const ushort* __restrict__ X,
                                             const ushort* __restrict__ Wqt,
                                             const ushort* __restrict__ Wkt,
                                             const ushort* __restrict__ Wvt,
                                             ushort* __restrict__ Q,
                                             ushort* __restrict__ K,
                                             ushort* __restrict__ V) {
  __shared__ ushort Al[2 * 4096];
  __shared__ ushort Bl[2 * 4096];
  const ushort* Wt; ushort* Out;
  switch (blockIdx.z) {
    case 0: Wt = Wqt; Out = Q; break;
    case 1: Wt = Wkt; Out = K; break;
    default: Wt = Wvt; Out = V; break;
  }
  f32x4 acc[4][4];
  gemm_tile(X + (size_t)blockIdx.x * 128 * DD, Wt + (size_t)blockIdx.y * 128 * DD, Al, Bl, acc);
  int lane = threadIdx.x & 63, w = threadIdx.x >> 6;
  int wm = w >> 1, wn = w & 1, lrow = lane & 15, lgrp = lane >> 4;
  int m0 = blockIdx.x * 128 + wm * 64, n0 = blockIdx.y * 128 + wn * 64;
#pragma unroll
  for (int i = 0; i < 4; i++)
#pragma unroll
    for (int j = 0; j < 4; j++)
#pragma unroll
      for (int r = 0; r < 4; r++) {
        int row = m0 + i * 16 + lgrp * 4 + r;   // global m (b*S+s)
        int col = n0 + j * 16 + lrow;            // global n (h*64+hd)
        int b = row >> 11, s = row & 2047, h = col >> 6, hd = col & 63;
        Out[(((size_t)(b * HH + h) * SS) + s) * HDD + hd] = f2bf(acc[i][j][r]);
      }
}

// ---------------- flash attention v2 ----------------
// Swapped QK^T (S^T = K·Q^T) for lane-local softmax; V^T from global; XOR-swizzled LDS;
// global_load_lds staging with pre-swizzled source; 2-phase double buffer.
// Block: 128 q rows (4 waves x 32), KV tile 64.
#define QB 128
#define KVB 64

__global__ __launch_bounds__(256) void k_attn(const ushort* __restrict__ Q,
                                              const ushort* __restrict__ K,
                                              const ushort* __restrict__ Vt,
                                              ushort* __restrict__ Ctx) {
  __shared__ ushort Kl[2][64 * 64];
  __shared__ ushort Vl[2][64 * 64];
  __shared__ ushort Pl[4][32 * 64];
  int bh = blockIdx.y;
  int b = bh >> 4, h = bh & 15;
  int bxx = gridDim.x - 1 - blockIdx.x;   // heavy blocks first
  int qb = bxx * QB;
  int tid = threadIdx.x, lane = tid & 63, w = tid >> 6;
  int lrow = lane & 15, lgrp = lane >> 4;
  int qw0 = qb + w * 32;

  // staging lane params (pre-swizzled global source, linear LDS dest)
  int srow = lane >> 3;                          // 0..7 = row&7 of dest row
  int scolb = ((lane & 7) * 16) ^ (srow << 4);   // swizzled source byte col
  const char* K8 = (const char*)(K + (size_t)bh * SS * HDD);
  const char* V8 = (const char*)(Vt + (size_t)bh * HDD * SS);

  // Q fragments (B-operand: lane holds Q[q = qt*16+lrow][d-block lgrp, half c])
  short8 qf[2][2];
#pragma unroll
  for (int qt = 0; qt < 2; qt++)
#pragma unroll
    for (int c = 0; c < 2; c++)
      qf[qt][c] = *(const short8*)(Q + ((size_t)bh * SS + qb + w * 32 + qt * 16 + lrow) * HDD + lgrp * 8 + 32 * c);

  f32x4 o[2][4];
#pragma unroll
  for (int qt = 0; qt < 2; qt++)
#pragma unroll
    for (int nt = 0; nt < 4; nt++)
#pragma unroll
      for (int r = 0; r < 4; r++) o[qt][nt][r] = 0.f;
  float m_run[2] = {-1e30f, -1e30f}, l_run[2] = {0.f, 0.f};

  int ntk = (qb + QB) / KVB;

  // swizzled read addressing (element units): elem pos = elem ^ ((row&7)<<3)
  int kswz = (lrow & 7) << 3;
  int colE[2];
  colE[0] = (lgrp * 8) ^ kswz;
  colE[1] = (lgrp * 8 + 32) ^ kswz;
  ushort* Plw = &Pl[w][0];

  // prologue: stage tile 0 into buf 0 (wave w: insts w, w+4 for K and V)
#pragma unroll
  for (int ii = 0; ii < 2; ii++) {
    int i = w + ii * 4;
    gload16(&Kl[0][i * 512], K8 + (size_t)(i * 8 + srow) * 128 + scolb);
    gload16(&Vl[0][i * 512], V8 + (size_t)(i * 8 + srow) * (SS * 2) + scolb);
  }
  __syncthreads();

  for (int kt = 0; kt < ntk; kt++) {
    int cur = kt & 1;
    if (kt + 1 < ntk) {
      int kb2 = (kt + 1) * KVB;
#pragma unroll
      for (int ii = 0; ii < 2; ii++) {
        int i = w + ii * 4;
        gload16(&Kl[cur ^ 1][i * 512], K8 + (size_t)(kb2 + i * 8 + srow) * 128 + scolb);
        gload16(&Vl[cur ^ 1][i * 512], V8 + (size_t)(i * 8 + srow) * (SS * 2) + (size_t)kb2 * 2 + scolb);
      }
    }
    int kb = kt * KVB;
    if (kb <= qw0 + 31) {   // wave has unmasked work in this tile
      // K fragments (A-operand)
      short8 kf[4][2];
#pragma unroll
      for (int t = 0; t < 4; t++)
#pragma unroll
        for (int c = 0; c < 2; c++)
          kf[t][c] = *(const short8*)&Kl[cur][(16 * t + lrow) * 64 + colE[c]];
      // S^T = K·Q^T : lane holds S^T[kv=16t+lgrp*4+r][q=qt*16+lrow]
      f32x4 st[2][4];
#pragma unroll
      for (int qt = 0; qt < 2; qt++)
#pragma unroll
        for (int t = 0; t < 4; t++) {
          f32x4 z;
#pragma unroll
          for (int r = 0; r < 4; r++) z[r] = 0.f;
          z = __builtin_amdgcn_mfma_f32_16x16x32_bf16(kf[t][0], qf[qt][0], z, 0, 0, 0);
          z = __builtin_amdgcn_mfma_f32_16x16x32_bf16(kf[t][1], qf[qt][1], z, 0, 0, 0);
          st[qt][t] = z;
        }
      bool full = (kb + 63 <= qw0);  // tile entirely below diagonal for this wave
#pragma unroll
      for (int qt = 0; qt < 2; qt++) {
        int qg = qw0 + qt * 16 + lrow;
        int lim = qg - kb - lgrp * 4;       // mask if 16t + r > lim
        float rm = -3e38f;
#pragma unroll
        for (int t = 0; t < 4; t++)
#pragma unroll
          for (int r = 0; r < 4; r++) {
            float v = st[qt][t][r] * 0.125f;
            if (!full && (16 * t + r > lim)) v = -3e38f;
            st[qt][t][r] = v;
            rm = fmaxf(rm, v);
          }
        rm = fmaxf(rm, __shfl_xor(rm, 16));
        rm = fmaxf(rm, __shfl_xor(rm, 32));
        float mn = fmaxf(m_run[qt], rm);
        float sca = __expf(m_run[qt] - mn);
        m_run[qt] = mn;
        float rs = 0.f;
        uint2 pk[4];
#pragma unroll
        for (int t = 0; t < 4; t++) {
          float e0 = __expf(st[qt][t][0] - mn);
          float e1 = __expf(st[qt][t][1] - mn);
          float e2 = __expf(st[qt][t][2] - mn);
          float e3 = __expf(st[qt][t][3] - mn);
          rs += (e0 + e1) + (e2 + e3);
          pk[t].x = (uint)f2bf(e0) | ((uint)f2bf(e1) << 16);
          pk[t].y = (uint)f2bf(e2) | ((uint)f2bf(e3) << 16);
        }
        rs += __shfl_xor(rs, 16);
        rs += __shfl_xor(rs, 32);
        l_run[qt] = l_run[qt] * sca + rs;
        // write P^T->P: row q, elems 16t+lgrp*4..+3, swizzled
#pragma unroll
        for (int t = 0; t < 4; t++)
          *(uint2*)&Plw[(qt * 16 + lrow) * 64 + ((16 * t + lgrp * 4) ^ kswz)] = pk[t];
        // rescale O (lane's O rows are q = qt*16 + lgrp*4 + r)
#pragma unroll
        for (int r = 0; r < 4; r++) {
          float scr = __shfl(sca, (lane & 48) | (lgrp * 4 + r));
#pragma unroll
          for (int nt = 0; nt < 4; nt++) o[qt][nt][r] *= scr;
        }
      }
      // PV: O[q][hd] += P[q][kv] · V[kv][hd]
      short8 pa[2][2], vf[4][2];
#pragma unroll
      for (int qt = 0; qt < 2; qt++)
#pragma unroll
        for (int kc = 0; kc < 2; kc++)
          pa[qt][kc] = *(const short8*)&Plw[(qt * 16 + lrow) * 64 + colE[kc]];
#pragma unroll
      for (int nt = 0; nt < 4; nt++)
#pragma unroll
        for (int kc = 0; kc < 2; kc++)
          vf[nt][kc] = *(const short8*)&Vl[cur][(nt * 16 + lrow) * 64 + colE[kc]];
#pragma unroll
      for (int qt = 0; qt < 2; qt++)
#pragma unroll
        for (int nt = 0; nt < 4; nt++) {
          o[qt][nt] = __builtin_amdgcn_mfma_f32_16x16x32_bf16(pa[qt][0], vf[nt][0], o[qt][nt], 0, 0, 0);
          o[qt][nt] = __builtin_amdgcn_mfma_f32_16x16x32_bf16(pa[qt][1], vf[nt][1], o[qt][nt], 0, 0, 0);
        }
    }
    __syncthreads();
  }

  // epilogue
#pragma unroll
  for (int qt = 0; qt < 2; qt++) {
    float inv[4];
#pragma unroll
    for (int r = 0; r < 4; r++) {
      float li = __shfl(l_run[qt], (lane & 48) | (lgrp * 4 + r));
      inv[r] = 1.f / li;
    }
#pragma unroll
    for (int nt = 0; nt < 4; nt++)
#pragma unroll
      for (int r = 0; r < 4; r++) {
        int q = qb + w * 32 + qt * 16 + lgrp * 4 + r;
        int col = h * HDD + nt * 16 + lrow;
        Ctx[((size_t)b * SS + q) * DD + col] = f2bf(o[qt][nt][r] * inv[r]);
      }
  }
}

// ---------------- output projection: Ctx @ Wo -> out fp32 [B,S,D] ----------------
__global__ __launch_bounds__(256) void k_oproj(const ushort* __restrict__ Ctx,
                                               const ushort* __restrict__ Wot,
                                               float* __restrict__ Outp) {
  __shared__ ushort Al[2 * 4096];
  __shared__ ushort Bl[2 * 4096];
  f32x4 acc[4][4];
  gemm_tile(Ctx + (size_t)blockIdx.x * 128 * DD, Wot + (size_t)blockIdx.y * 128 * DD, Al, Bl, acc);
  int lane = threadIdx.x & 63, w = threadIdx.x >> 6;
  int wm = w >> 1, wn = w & 1, lrow = lane & 15, lgrp = lane >> 4;
  int m0 = blockIdx.x * 128 + wm * 64, n0 = blockIdx.y * 128 + wn * 64;
#pragma unroll
  for (int i = 0; i < 4; i++)
#pragma unroll
    for (int j = 0; j < 4; j++)
#pragma unroll
      for (int r = 0; r < 4; r++) {
        int row = m0 + i * 16 + lgrp * 4 + r;
        int col = n0 + j * 16 + lrow;
        Outp[(size_t)row * DD + col] = acc[i][j][r];
      }
}

// ---------------- launch ----------------
extern "C" void kernel_launch(void* const* d_in, const int* in_sizes, int n_in,
                              void* d_out, int out_size, void* d_ws, size_t ws_size,
                              hipStream_t stream) {
  const float* states = (const float*)d_in[0];
  // d_in[1] = mask (causal tril) — hardcoded in kernel
  const float* Wq = (const float*)d_in[2];
  const float* Wk = (const float*)d_in[3];
  const float* Wv = (const float*)d_in[4];
  const float* Wo = (const float*)d_in[5];
  float* outp = (float*)d_out;

  char* ws = (char*)d_ws;
  const size_t XBF = 0;                 // 16 MB (X bf16), later reused as Vt
  const size_t WQT = 16777216;          // 2 MB each
  const size_t WKT = WQT + 2097152;
  const size_t WVT = WKT + 2097152;
  const size_t WOT = WVT + 2097152;
  const size_t QO  = WOT + 2097152;     // 16 MB each
  const size_t KO  = QO + 16777216;
  const size_t VO  = KO + 16777216;
  const size_t CTX = VO + 16777216;     // 16 MB

  ushort* Xbf = (ushort*)(ws + XBF);
  ushort* Wqt = (ushort*)(ws + WQT);
  ushort* Wkt = (ushort*)(ws + WKT);
  ushort* Wvt = (ushort*)(ws + WVT);
  ushort* Wot = (ushort*)(ws + WOT);
  ushort* Qb  = (ushort*)(ws + QO);
  ushort* Kb  = (ushort*)(ws + KO);
  ushort* Vb  = (ushort*)(ws + VO);
  ushort* Vtb = (ushort*)(ws + XBF);    // reuse X region after k_qkv
  ushort* Ctb = (ushort*)(ws + CTX);

  k_convert<<<(MM * DD / 4 + 255) / 256, 256, 0, stream>>>(states, Xbf, MM * DD / 4);
  k_transpose<<<dim3(32, 32, 4), dim3(32, 8), 0, stream>>>(Wq, Wk, Wv, Wo, Wqt, Wkt, Wvt, Wot);
  k_qkv<<<dim3(MM / 128, DD / 128, 3), 256, 0, stream>>>(Xbf, Wqt, Wkt, Wvt, Qb, Kb, Vb);
  k_vtrans<<<dim3(SS / 64, BB * HH), 256, 0, stream>>>(Vb, Vtb);
  k_attn<<<dim3(SS / QB, BB * HH), 256, 0, stream>>>(Qb, Kb, Vtb, Ctb);
  k_oproj<<<dim3(MM / 128, DD / 128), 256, 0, stream>>>(Ctb, Wot, outp);
}

// Round 3
// 188.370 us; speedup vs baseline: 2.3127x; 1.5034x over previous
//
#include <hip/hip_runtime.h>
#include <hip/hip_bf16.h>

// Problem dims (AttentionLayer): B=4, S=2048, D=1024, H=16, HD=64
#define BB 4
#define SS 2048
#define DD 1024
#define HH 16
#define HDD 64
#define MM (BB*SS)   // 8192 rows

typedef __attribute__((ext_vector_type(8))) short short8;
typedef __attribute__((ext_vector_type(4))) float f32x4;
typedef __attribute__((ext_vector_type(4))) int int4v;
typedef __attribute__((ext_vector_type(4))) short bf16x4;

__device__ __forceinline__ ushort f2bf(float f) {
  union { float f; uint u; } v; v.f = f;
  uint u = v.u;
  uint r = (u + 0x7FFFu + ((u >> 16) & 1u)) >> 16;  // RNE
  return (ushort)r;
}

__device__ __forceinline__ float exp2f_fast(float x) {
#if __has_builtin(__builtin_amdgcn_exp2f)
  return __builtin_amdgcn_exp2f(x);
#else
  float r; asm("v_exp_f32 %0, %1" : "=v"(r) : "v"(x)); return r;
#endif
}

__device__ __forceinline__ bf16x4 pack4bf(float a, float b, float c, float d) {
  union { __hip_bfloat162 h2[2]; bf16x4 s; } u;
  u.h2[0] = __float22bfloat162_rn(make_float2(a, b));
  u.h2[1] = __float22bfloat162_rn(make_float2(c, d));
  return u.s;
}

__device__ __forceinline__ f32x4 mfma16(bf16x4 a, bf16x4 b, f32x4 c) {
#if __has_builtin(__builtin_amdgcn_mfma_f32_16x16x16bf16_1k)
  return __builtin_amdgcn_mfma_f32_16x16x16bf16_1k(a, b, c, 0, 0, 0);
#else
  f32x4 d;
  asm volatile("s_nop 1\n\tv_mfma_f32_16x16x16_bf16 %0, %1, %2, %3\n\ts_nop 7\n\ts_nop 3"
               : "=v"(d) : "v"(a), "v"(b), "v"(c));
  return d;
#endif
}

__device__ __forceinline__ void gload16(void* lds, const void* g) {
  __builtin_amdgcn_global_load_lds((const __attribute__((address_space(1))) void*)g,
                                   (__attribute__((address_space(3))) void*)lds, 16, 0, 0);
}

// ---------------- prep: fp32 -> bf16 convert (states) ----------------
__global__ __launch_bounds__(256) void k_convert(const float* __restrict__ in,
                                                 ushort* __restrict__ out, int n4) {
  int i = blockIdx.x * 256 + threadIdx.x;
  if (i >= n4) return;
  float4 v = ((const float4*)in)[i];
  uint lo = (uint)f2bf(v.x) | ((uint)f2bf(v.y) << 16);
  uint hi = (uint)f2bf(v.z) | ((uint)f2bf(v.w) << 16);
  ((uint2*)out)[i] = make_uint2(lo, hi);
}

// ---------------- prep: transpose+convert weights W[K][N] -> Wt[N][K] bf16 ----------------
// Wq additionally scaled by 0.125*log2(e) so attention softmax runs in exp2 domain.
__global__ __launch_bounds__(256) void k_transpose(const float* __restrict__ W0, const float* __restrict__ W1,
                                                   const float* __restrict__ W2, const float* __restrict__ W3,
                                                   ushort* __restrict__ T0, ushort* __restrict__ T1,
                                                   ushort* __restrict__ T2, ushort* __restrict__ T3) {
  __shared__ float t[32][33];
  const float* W; ushort* T;
  switch (blockIdx.z) {
    case 0: W = W0; T = T0; break;
    case 1: W = W1; T = T1; break;
    case 2: W = W2; T = T2; break;
    default: W = W3; T = T3; break;
  }
  float scale = (blockIdx.z == 0) ? 0.18033688011112042f : 1.0f;  // 0.125 * log2(e)
  int tx = threadIdx.x, ty = threadIdx.y;   // 32 x 8
  int x = blockIdx.x * 32 + tx;
  int y0 = blockIdx.y * 32;
#pragma unroll
  for (int j = 0; j < 32; j += 8) t[ty + j][tx] = W[(y0 + ty + j) * DD + x];
  __syncthreads();
#pragma unroll
  for (int j = 0; j < 32; j += 8)
    T[(blockIdx.x * 32 + ty + j) * DD + y0 + tx] = f2bf(t[tx][ty + j] * scale);
}

// ---------------- V transpose: V[bh][s][64] -> Vt[bh][64][S] (bf16) ----------------
__global__ __launch_bounds__(256) void k_vtrans(const ushort* __restrict__ V,
                                                ushort* __restrict__ Vt) {
  __shared__ ushort t[64][72];
  int bh = blockIdx.y;
  int s0 = blockIdx.x * 64;
  int tid = threadIdx.x;
  int r = tid >> 3, c8 = (tid & 7) * 8;
  const ushort* vp = V + (size_t)bh * SS * HDD;
#pragma unroll
  for (int p = 0; p < 2; p++) {
    int row = r + p * 32;
    *(int4v*)&t[row][c8] = *(const int4v*)(vp + (size_t)(s0 + row) * HDD + c8);
  }
  __syncthreads();
  int hd = tid >> 2, sc = (tid & 3) * 16;
  ushort tmp[16];
#pragma unroll
  for (int j = 0; j < 16; j++) tmp[j] = t[sc + j][hd];
  ushort* op = Vt + ((size_t)bh * HDD + hd) * SS + s0 + sc;
  *(int4v*)op = *(int4v*)tmp;
  *(int4v*)(op + 8) = *(int4v*)(tmp + 8);
}

// ---------------- shared GEMM mainloop (m97-style): C[128,128] = A[128,K] * Bt[128,K]^T ----------------
__device__ __forceinline__ void gemm_tile(const ushort* __restrict__ Arow,
                                          const ushort* __restrict__ Brow,
                                          ushort* Al, ushort* Bl,   // each [2][128*32]
                                          f32x4 acc[4][4]) {
  int tid = threadIdx.x;
  int lane = tid & 63, w = tid >> 6;
  int wm = w >> 1, wn = w & 1;
  int lrow = lane & 15, lgrp = lane >> 4;
#pragma unroll
  for (int i = 0; i < 4; i++)
#pragma unroll
    for (int j = 0; j < 4; j++)
#pragma unroll
      for (int r = 0; r < 4; r++) acc[i][j][r] = 0.f;

  int srow = lane >> 2;            // 0..15
  int scolb = (lane & 3) * 16;     // byte col within 64B row-chunk
  const char* A8 = (const char*)Arow;
  const char* B8 = (const char*)Brow;

#pragma unroll
  for (int ii = 0; ii < 2; ii++) {
    int i = w * 2 + ii;
    gload16(Al + i * 512, A8 + (size_t)(i * 16 + srow) * (DD * 2) + scolb);
    gload16(Bl + i * 512, B8 + (size_t)(i * 16 + srow) * (DD * 2) + scolb);
  }
  __syncthreads();

  for (int kk = 0; kk < DD; kk += 32) {
    int cur = (kk >> 5) & 1;
    if (kk + 32 < DD) {
#pragma unroll
      for (int ii = 0; ii < 2; ii++) {
        int i = w * 2 + ii;
        gload16(Al + (cur ^ 1) * 4096 + i * 512,
                A8 + (size_t)(i * 16 + srow) * (DD * 2) + (kk + 32) * 2 + scolb);
        gload16(Bl + (cur ^ 1) * 4096 + i * 512,
                B8 + (size_t)(i * 16 + srow) * (DD * 2) + (kk + 32) * 2 + scolb);
      }
    }
    short8 a[4], b[4];
#pragma unroll
    for (int i = 0; i < 4; i++) a[i] = *(const short8*)&Al[cur * 4096 + (wm * 64 + i * 16 + lrow) * 32 + lgrp * 8];
#pragma unroll
    for (int j = 0; j < 4; j++) b[j] = *(const short8*)&Bl[cur * 4096 + (wn * 64 + j * 16 + lrow) * 32 + lgrp * 8];
#pragma unroll
    for (int i = 0; i < 4; i++)
#pragma unroll
      for (int j = 0; j < 4; j++)
        acc[i][j] = __builtin_amdgcn_mfma_f32_16x16x32_bf16(a[i], b[j], acc[i][j], 0, 0, 0);
    __syncthreads();
  }
}

// ---------------- QKV projection ----------------
__global__ __launch_bounds__(256) void k_qkv(const ushort* __restrict__ X,
                                             const ushort* __restrict__ Wqt,
                                             const ushort* __restrict__ Wkt,
                                             const ushort* __restrict__ Wvt,
                                             ushort* __restrict__ Q,
                                             ushort* __restrict__ K,
                                             ushort* __restrict__ V) {
  __shared__ ushort Al[2 * 4096];
  __shared__ ushort Bl[2 * 4096];
  const ushort* Wt; ushort* Out;
  switch (blockIdx.z) {
    case 0: Wt = Wqt; Out = Q; break;
    case 1: Wt = Wkt; Out = K; break;
    default: Wt = Wvt; Out = V; break;
  }
  f32x4 acc[4][4];
  gemm_tile(X + (size_t)blockIdx.x * 128 * DD, Wt + (size_t)blockIdx.y * 128 * DD, Al, Bl, acc);
  int lane = threadIdx.x & 63, w = threadIdx.x >> 6;
  int wm = w >> 1, wn = w & 1, lrow = lane & 15, lgrp = lane >> 4;
  int m0 = blockIdx.x * 128 + wm * 64, n0 = blockIdx.y * 128 + wn * 64;
#pragma unroll
  for (int i = 0; i < 4; i++)
#pragma unroll
    for (int j = 0; j < 4; j++)
#pragma unroll
      for (int r = 0; r < 4; r++) {
        int row = m0 + i * 16 + lgrp * 4 + r;   // global m (b*S+s)
        int col = n0 + j * 16 + lrow;            // global n (h*64+hd)
        int b = row >> 11, s = row & 2047, h = col >> 6, hd = col & 63;
        Out[(((size_t)(b * HH + h) * SS) + s) * HDD + hd] = f2bf(acc[i][j][r]);
      }
}

// ---------------- flash attention v3 ----------------
// O^T formulation: S^T = K·Q^T (16x16x32), P^T stays in registers, PV via
// 16x16x16 mfma (A=V^T, B=P^T) -> O^T[hd][q]. Stats and O columns lane-local.
// Causal pairing: block bx does q-tiles (15-bx) then bx -> 34 KV-tiles/block.
#define QB 128
#define KVB 64
#define NQT (SS / QB)   // 16

__global__ __launch_bounds__(256) void k_attn(const ushort* __restrict__ Q,
                                              const ushort* __restrict__ K,
                                              const ushort* __restrict__ Vt,
                                              ushort* __restrict__ Ctx) {
  __shared__ ushort Kl[2][4096];
  __shared__ ushort Vl[2][4096];
  int bh = blockIdx.y;
  int b = bh >> 4, h = bh & 15;
  int bx = blockIdx.x;           // 0..7
  int tid = threadIdx.x, lane = tid & 63, w = tid >> 6;
  int lrow = lane & 15, lgrp = lane >> 4;

  // staging lane params (pre-swizzled global source, linear LDS dest)
  int srow = lane >> 3;                          // 0..7
  int scolb = ((lane & 7) * 16) ^ (srow << 4);   // swizzled source byte col
  const char* K8 = (const char*)(K + (size_t)bh * SS * HDD);
  const char* V8 = (const char*)(Vt + (size_t)bh * HDD * SS);

  int kswz = (lrow & 7) << 3;
  int colE[2];
  colE[0] = (lgrp * 8) ^ kswz;
  colE[1] = (lgrp * 8 + 32) ^ kswz;

  for (int ph = 0; ph < 2; ph++) {
    int qx = ph == 0 ? (NQT - 1 - bx) : bx;   // heavy half first
    int qb = qx * QB;
    int qw0 = qb + w * 32;
    int ntk = 2 * qx + 2;

    // Q fragments (B-operand of S^T mfma: lane holds Q[q=qt*16+lrow][.])
    short8 qf[2][2];
#pragma unroll
    for (int qt = 0; qt < 2; qt++)
#pragma unroll
      for (int c = 0; c < 2; c++)
        qf[qt][c] = *(const short8*)(Q + ((size_t)bh * SS + qb + w * 32 + qt * 16 + lrow) * HDD + lgrp * 8 + 32 * c);

    f32x4 o[2][4];
#pragma unroll
    for (int qt = 0; qt < 2; qt++)
#pragma unroll
      for (int nt = 0; nt < 4; nt++)
#pragma unroll
        for (int r = 0; r < 4; r++) o[qt][nt][r] = 0.f;
    float m_run[2] = {-1e30f, -1e30f}, l_run[2] = {0.f, 0.f};

    // prologue: stage tile 0 into buf 0
#pragma unroll
    for (int ii = 0; ii < 2; ii++) {
      int i = w + ii * 4;
      gload16(&Kl[0][i * 512], K8 + (size_t)(i * 8 + srow) * 128 + scolb);
      gload16(&Vl[0][i * 512], V8 + (size_t)(i * 8 + srow) * (SS * 2) + scolb);
    }
    __syncthreads();

    for (int kt = 0; kt < ntk; kt++) {
      int cur = kt & 1;
      if (kt + 1 < ntk) {
        int kb2 = (kt + 1) * KVB;
#pragma unroll
        for (int ii = 0; ii < 2; ii++) {
          int i = w + ii * 4;
          gload16(&Kl[cur ^ 1][i * 512], K8 + (size_t)(kb2 + i * 8 + srow) * 128 + scolb);
          gload16(&Vl[cur ^ 1][i * 512], V8 + (size_t)(i * 8 + srow) * (SS * 2) + (size_t)kb2 * 2 + scolb);
        }
      }
      int kb = kt * KVB;
      if (kb <= qw0 + 31) {
        // K fragments (A-operand)
        short8 kf[4][2];
#pragma unroll
        for (int t = 0; t < 4; t++)
#pragma unroll
          for (int c = 0; c < 2; c++)
            kf[t][c] = *(const short8*)&Kl[cur][(16 * t + lrow) * 64 + colE[c]];

        bf16x4 pk[2][4];
#pragma unroll
        for (int qt = 0; qt < 2; qt++) {
          // S^T tile: lane holds S^T[kv=16t+4*lgrp+r][q=qt*16+lrow], exp2 domain
          f32x4 st[4];
#pragma unroll
          for (int t = 0; t < 4; t++) {
            f32x4 z;
#pragma unroll
            for (int r = 0; r < 4; r++) z[r] = 0.f;
            z = __builtin_amdgcn_mfma_f32_16x16x32_bf16(kf[t][0], qf[qt][0], z, 0, 0, 0);
            z = __builtin_amdgcn_mfma_f32_16x16x32_bf16(kf[t][1], qf[qt][1], z, 0, 0, 0);
            st[t] = z;
          }
          if (kb + 63 > qw0) {  // diagonal tile: apply causal mask (wave-uniform branch)
            int lim = qw0 + qt * 16 + lrow - kb - lgrp * 4;
#pragma unroll
            for (int t = 0; t < 4; t++)
#pragma unroll
              for (int r = 0; r < 4; r++)
                if (16 * t + r > lim) st[t][r] = -1e30f;
          }
          float rm = -1e30f;
#pragma unroll
          for (int t = 0; t < 4; t++) {
            float m01 = fmaxf(st[t][0], st[t][1]);
            float m23 = fmaxf(st[t][2], st[t][3]);
            rm = fmaxf(rm, fmaxf(m01, m23));
          }
          rm = fmaxf(rm, __shfl_xor(rm, 16));
          rm = fmaxf(rm, __shfl_xor(rm, 32));
          bool need = rm > m_run[qt] + 8.f;   // defer-max (T13), exp2 domain
          if (__any(need)) {
            float mn = need ? rm : m_run[qt];
            float sca = exp2f_fast(m_run[qt] - mn);
            m_run[qt] = mn;
            l_run[qt] *= sca;
#pragma unroll
            for (int nt = 0; nt < 4; nt++)
#pragma unroll
              for (int r = 0; r < 4; r++) o[qt][nt][r] *= sca;
          }
          float m = m_run[qt];
          float rs = 0.f;
#pragma unroll
          for (int t = 0; t < 4; t++) {
            float e0 = exp2f_fast(st[t][0] - m);
            float e1 = exp2f_fast(st[t][1] - m);
            float e2 = exp2f_fast(st[t][2] - m);
            float e3 = exp2f_fast(st[t][3] - m);
            rs += (e0 + e1) + (e2 + e3);
            pk[qt][t] = pack4bf(e0, e1, e2, e3);
          }
          rs += __shfl_xor(rs, 16);
          rs += __shfl_xor(rs, 32);
          l_run[qt] += rs;
        }

        // PV: O^T[hd][q] += V^T[hd][kv] * P^T[kv][q], K=16 chunks, P in-register
#pragma unroll
        for (int nt = 0; nt < 4; nt++) {
#pragma unroll
          for (int t = 0; t < 4; t++) {
            bf16x4 va = *(const bf16x4*)&Vl[cur][(nt * 16 + lrow) * 64 + ((16 * t + lgrp * 4) ^ kswz)];
            o[0][nt] = mfma16(va, pk[0][t], o[0][nt]);
            o[1][nt] = mfma16(va, pk[1][t], o[1][nt]);
          }
        }
      }
      __syncthreads();
    }

    // epilogue: lane owns O^T column q = qw0 + qt*16 + lrow
#pragma unroll
    for (int qt = 0; qt < 2; qt++) {
      float inv = 1.f / l_run[qt];
      int q = qb + w * 32 + qt * 16 + lrow;
      ushort* base = Ctx + ((size_t)b * SS + q) * DD + h * HDD;
#pragma unroll
      for (int nt = 0; nt < 4; nt++) {
        bf16x4 s = pack4bf(o[qt][nt][0] * inv, o[qt][nt][1] * inv,
                           o[qt][nt][2] * inv, o[qt][nt][3] * inv);
        *(bf16x4*)(base + nt * 16 + lgrp * 4) = s;
      }
    }
    __syncthreads();
  }
}

// ---------------- output projection: Ctx @ Wo -> out fp32 [B,S,D] ----------------
__global__ __launch_bounds__(256) void k_oproj(const ushort* __restrict__ Ctx,
                                               const ushort* __restrict__ Wot,
                                               float* __restrict__ Outp) {
  __shared__ ushort Al[2 * 4096];
  __shared__ ushort Bl[2 * 4096];
  f32x4 acc[4][4];
  gemm_tile(Ctx + (size_t)blockIdx.x * 128 * DD, Wot + (size_t)blockIdx.y * 128 * DD, Al, Bl, acc);
  int lane = threadIdx.x & 63, w = threadIdx.x >> 6;
  int wm = w >> 1, wn = w & 1, lrow = lane & 15, lgrp = lane >> 4;
  int m0 = blockIdx.x * 128 + wm * 64, n0 = blockIdx.y * 128 + wn * 64;
#pragma unroll
  for (int i = 0; i < 4; i++)
#pragma unroll
    for (int j = 0; j < 4; j++)
#pragma unroll
      for (int r = 0; r < 4; r++) {
        int row = m0 + i * 16 + lgrp * 4 + r;
        int col = n0 + j * 16 + lrow;
        Outp[(size_t)row * DD + col] = acc[i][j][r];
      }
}

// ---------------- launch ----------------
extern "C" void kernel_launch(void* const* d_in, const int* in_sizes, int n_in,
                              void* d_out, int out_size, void* d_ws, size_t ws_size,
                              hipStream_t stream) {
  const float* states = (const float*)d_in[0];
  // d_in[1] = mask (causal tril) — hardcoded in kernel
  const float* Wq = (const float*)d_in[2];
  const float* Wk = (const float*)d_in[3];
  const float* Wv = (const float*)d_in[4];
  const float* Wo = (const float*)d_in[5];
  float* outp = (float*)d_out;

  char* ws = (char*)d_ws;
  const size_t XBF = 0;                 // 16 MB (X bf16), later reused as Vt
  const size_t WQT = 16777216;          // 2 MB each
  const size_t WKT = WQT + 2097152;
  const size_t WVT = WKT + 2097152;
  const size_t WOT = WVT + 2097152;
  const size_t QO  = WOT + 2097152;     // 16 MB each
  const size_t KO  = QO + 16777216;
  const size_t VO  = KO + 16777216;
  const size_t CTX = VO + 16777216;     // 16 MB

  ushort* Xbf = (ushort*)(ws + XBF);
  ushort* Wqt = (ushort*)(ws + WQT);
  ushort* Wkt = (ushort*)(ws + WKT);
  ushort* Wvt = (ushort*)(ws + WVT);
  ushort* Wot = (ushort*)(ws + WOT);
  ushort* Qb  = (ushort*)(ws + QO);
  ushort* Kb  = (ushort*)(ws + KO);
  ushort* Vb  = (ushort*)(ws + VO);
  ushort* Vtb = (ushort*)(ws + XBF);    // reuse X region after k_qkv
  ushort* Ctb = (ushort*)(ws + CTX);

  k_convert<<<(MM * DD / 4 + 255) / 256, 256, 0, stream>>>(states, Xbf, MM * DD / 4);
  k_transpose<<<dim3(32, 32, 4), dim3(32, 8), 0, stream>>>(Wq, Wk, Wv, Wo, Wqt, Wkt, Wvt, Wot);
  k_qkv<<<dim3(MM / 128, DD / 128, 3), 256, 0, stream>>>(Xbf, Wqt, Wkt, Wvt, Qb, Kb, Vb);
  k_vtrans<<<dim3(SS / 64, BB * HH), 256, 0, stream>>>(Vb, Vtb);
  k_attn<<<dim3(SS / QB / 2, BB * HH), 256, 0, stream>>>(Qb, Kb, Vtb, Ctb);
  k_oproj<<<dim3(MM / 128, DD / 128), 256, 0, stream>>>(Ctb, Wot, outp);
}